// Round 1
// baseline (778.051 us; speedup 1.0000x reference)
//
#include <hip/hip_runtime.h>
#include <hip/hip_bf16.h>

// Problem sizes (fixed by reference)
#define N_NODES   100000
#define N_EDGES   640000
#define NUM_GRAPHS 128
#define NUM_FEAT  128
#define HIDDEN    16
#define NUM_CLS   10

// ---------------- K1: y = x @ W1   [N,128] @ [128,16] -> [N,16] ----------------
#define MM1_ROWS 64
__global__ __launch_bounds__(256) void k_mm1(const float* __restrict__ x,
                                             const float* __restrict__ W1,
                                             float* __restrict__ y, int N) {
    __shared__ float sx[MM1_ROWS][129];   // +1 pad breaks bank aliasing
    __shared__ float sw[NUM_FEAT * HIDDEN];
    const int t = threadIdx.x;
    const int rowbase = blockIdx.x * MM1_ROWS;
    const int nrows = min(MM1_ROWS, N - rowbase);

    for (int i = t; i < NUM_FEAT * HIDDEN; i += 256) sw[i] = W1[i];

    // coalesced float4 load of the x tile
    for (int i = t; i < nrows * 32; i += 256) {
        int r = i >> 5, q = i & 31;
        float4 v = ((const float4*)(x + (size_t)(rowbase + r) * NUM_FEAT))[q];
        sx[r][q * 4 + 0] = v.x; sx[r][q * 4 + 1] = v.y;
        sx[r][q * 4 + 2] = v.z; sx[r][q * 4 + 3] = v.w;
    }
    __syncthreads();

    const int r  = t >> 2;          // 0..63
    const int c0 = (t & 3) * 4;     // 0,4,8,12
    if (r < nrows) {
        float a0 = 0.f, a1 = 0.f, a2 = 0.f, a3 = 0.f;
        #pragma unroll 8
        for (int k = 0; k < NUM_FEAT; ++k) {
            float xv = sx[r][k];
            const float* wr = &sw[k * HIDDEN + c0];
            a0 += xv * wr[0]; a1 += xv * wr[1];
            a2 += xv * wr[2]; a3 += xv * wr[3];
        }
        float4 o = {a0, a1, a2, a3};
        ((float4*)(y + (size_t)(rowbase + r) * HIDDEN))[t & 3] = o;
    }
}

// ---------------- K2/K5: agg[dst] += y[src]  (4 threads per edge) ----------------
__global__ __launch_bounds__(256) void k_scatter(const int* __restrict__ ei,
                                                 const float* __restrict__ y,
                                                 float* __restrict__ agg, int E) {
    int t = blockIdx.x * 256 + threadIdx.x;
    int e = t >> 2, p = t & 3;
    if (e >= E) return;
    int s = ei[e];
    int d = ei[E + e];
    float4 v = ((const float4*)(y + (size_t)s * HIDDEN))[p];
    float* dp = agg + (size_t)d * HIDDEN + p * 4;
    atomicAdd(dp + 0, v.x);
    atomicAdd(dp + 1, v.y);
    atomicAdd(dp + 2, v.z);
    atomicAdd(dp + 3, v.w);
}

// ---------------- K3: C = relu(A + B + bias[c])  (float4 over N*16) ----------------
__global__ __launch_bounds__(256) void k_addrelu(const float* __restrict__ A,
                                                 const float* __restrict__ B,
                                                 const float* __restrict__ bias,
                                                 float* __restrict__ C, int n4) {
    int i = blockIdx.x * 256 + threadIdx.x;
    if (i >= n4) return;
    float4 a = ((const float4*)A)[i];
    float4 b = ((const float4*)B)[i];
    float4 bv = ((const float4*)bias)[i & 3];
    float4 o;
    o.x = fmaxf(a.x + b.x + bv.x, 0.f);
    o.y = fmaxf(a.y + b.y + bv.y, 0.f);
    o.z = fmaxf(a.z + b.z + bv.z, 0.f);
    o.w = fmaxf(a.w + b.w + bv.w, 0.f);
    ((float4*)C)[i] = o;
}

// ---------------- K4: y = h @ W2   [N,16] @ [16,16] ----------------
__global__ __launch_bounds__(256) void k_mm2(const float* __restrict__ h,
                                             const float* __restrict__ W2,
                                             float* __restrict__ y, int N) {
    __shared__ float sw[HIDDEN * HIDDEN];
    int t = threadIdx.x;
    if (t < HIDDEN * HIDDEN) sw[t] = W2[t];
    __syncthreads();
    int n = blockIdx.x * 256 + t;
    if (n >= N) return;
    float hv[HIDDEN];
    const float4* hp = (const float4*)(h + (size_t)n * HIDDEN);
    #pragma unroll
    for (int q = 0; q < 4; ++q) {
        float4 v = hp[q];
        hv[q * 4 + 0] = v.x; hv[q * 4 + 1] = v.y;
        hv[q * 4 + 2] = v.z; hv[q * 4 + 3] = v.w;
    }
    float acc[HIDDEN];
    #pragma unroll
    for (int c = 0; c < HIDDEN; ++c) acc[c] = 0.f;
    #pragma unroll
    for (int k = 0; k < HIDDEN; ++k) {
        float hk = hv[k];
        #pragma unroll
        for (int c = 0; c < HIDDEN; ++c) acc[c] += hk * sw[k * HIDDEN + c];
    }
    float4* yp = (float4*)(y + (size_t)n * HIDDEN);
    #pragma unroll
    for (int q = 0; q < 4; ++q) {
        float4 o = {acc[q * 4 + 0], acc[q * 4 + 1], acc[q * 4 + 2], acc[q * 4 + 3]};
        yp[q] = o;
    }
}

// ---------------- K6: h2 = relu(A+B+b2); pool into sums/counts ----------------
__global__ __launch_bounds__(256) void k_pool(const float* __restrict__ A,
                                              const float* __restrict__ B,
                                              const float* __restrict__ bias,
                                              const int* __restrict__ batch,
                                              float* __restrict__ sums,
                                              float* __restrict__ counts, int N) {
    int t = blockIdx.x * 256 + threadIdx.x;
    int n = t >> 2, p = t & 3;
    if (n >= N) return;
    int g = batch[n];
    float4 a = ((const float4*)(A + (size_t)n * HIDDEN))[p];
    float4 b = ((const float4*)(B + (size_t)n * HIDDEN))[p];
    float4 bv = ((const float4*)bias)[p];
    float hx = fmaxf(a.x + b.x + bv.x, 0.f);
    float hy = fmaxf(a.y + b.y + bv.y, 0.f);
    float hz = fmaxf(a.z + b.z + bv.z, 0.f);
    float hw = fmaxf(a.w + b.w + bv.w, 0.f);
    float* sp = sums + (size_t)g * HIDDEN + p * 4;
    atomicAdd(sp + 0, hx);
    atomicAdd(sp + 1, hy);
    atomicAdd(sp + 2, hz);
    atomicAdd(sp + 3, hw);
    if (p == 0) atomicAdd(&counts[g], 1.0f);
}

// ---------------- K7: out = (sums/counts) @ Wfc + bfc ----------------
__global__ __launch_bounds__(256) void k_fc(const float* __restrict__ sums,
                                            const float* __restrict__ counts,
                                            const float* __restrict__ Wfc,
                                            const float* __restrict__ bfc,
                                            float* __restrict__ out) {
    int t = blockIdx.x * 256 + threadIdx.x;
    if (t >= NUM_GRAPHS * NUM_CLS) return;
    int g = t / NUM_CLS, c = t % NUM_CLS;
    float inv = 1.0f / fmaxf(counts[g], 1.0f);
    float acc = bfc[c];
    #pragma unroll
    for (int k = 0; k < HIDDEN; ++k)
        acc += (sums[g * HIDDEN + k] * inv) * Wfc[k * NUM_CLS + c];
    out[t] = acc;
}

extern "C" void kernel_launch(void* const* d_in, const int* in_sizes, int n_in,
                              void* d_out, int out_size, void* d_ws, size_t ws_size,
                              hipStream_t stream) {
    const float* x    = (const float*)d_in[0];
    const int*   ei   = (const int*)d_in[1];   // [2, E] (src row then dst row)
    const int*   batch= (const int*)d_in[2];
    const float* W1   = (const float*)d_in[3];
    const float* b1   = (const float*)d_in[4];
    const float* W2   = (const float*)d_in[5];
    const float* b2   = (const float*)d_in[6];
    const float* Wfc  = (const float*)d_in[7];
    const float* bfc  = (const float*)d_in[8];
    float* out = (float*)d_out;

    const size_t NB = (size_t)N_NODES * HIDDEN * sizeof(float);   // 6.4 MB
    char* ws = (char*)d_ws;
    float* A     = (float*)(ws);
    float* B     = (float*)(ws + NB);
    float* C     = (float*)(ws + 2 * NB);
    float* sums  = (float*)(ws + 3 * NB);
    float* counts= (float*)(ws + 3 * NB + (size_t)NUM_GRAPHS * HIDDEN * sizeof(float));

    const int n4 = N_NODES * HIDDEN / 4;                 // 400000
    const int gridElem = (n4 + 255) / 256;               // 1563
    const int gridMM1  = (N_NODES + MM1_ROWS - 1) / MM1_ROWS;
    const int gridScat = (N_EDGES * 4 + 255) / 256;      // 10000
    const int gridMM2  = (N_NODES + 255) / 256;
    const int gridPool = (N_NODES * 4 + 255) / 256;

    // zero agg buffer + pooling accumulators
    hipMemsetAsync(B, 0, NB, stream);
    hipMemsetAsync(sums, 0, (size_t)(NUM_GRAPHS * HIDDEN + NUM_GRAPHS) * sizeof(float), stream);

    // layer 1: A = x@W1 ; B = scatter(A) ; C = relu(A+B+b1)
    k_mm1<<<gridMM1, 256, 0, stream>>>(x, W1, A, N_NODES);
    k_scatter<<<gridScat, 256, 0, stream>>>(ei, A, B, N_EDGES);
    k_addrelu<<<gridElem, 256, 0, stream>>>(A, B, b1, C, n4);

    // layer 2: A = C@W2 ; B = scatter(A) ; pool(relu(A+B+b2))
    hipMemsetAsync(B, 0, NB, stream);
    k_mm2<<<gridMM2, 256, 0, stream>>>(C, W2, A, N_NODES);
    k_scatter<<<gridScat, 256, 0, stream>>>(ei, A, B, N_EDGES);
    k_pool<<<gridPool, 256, 0, stream>>>(A, B, b2, batch, sums, counts, N_NODES);

    // FC head
    k_fc<<<(NUM_GRAPHS * NUM_CLS + 255) / 256, 256, 0, stream>>>(sums, counts, Wfc, bfc, out);
}

// Round 2
// 319.282 us; speedup vs baseline: 2.4369x; 2.4369x over previous
//
#include <hip/hip_runtime.h>
#include <hip/hip_bf16.h>

// Problem sizes (fixed by reference)
#define N_NODES   100000
#define N_EDGES   640000
#define NUM_GRAPHS 128
#define NUM_FEAT  128
#define HIDDEN    16
#define NUM_CLS   10

// ---------------- K1: y = x @ W1   [N,128] @ [128,16] -> [N,16] ----------------
#define MM1_ROWS 64
__global__ __launch_bounds__(256) void k_mm1(const float* __restrict__ x,
                                             const float* __restrict__ W1,
                                             float* __restrict__ y, int N) {
    __shared__ float sx[MM1_ROWS][129];   // +1 pad breaks bank aliasing
    __shared__ float sw[NUM_FEAT * HIDDEN];
    const int t = threadIdx.x;
    const int rowbase = blockIdx.x * MM1_ROWS;
    const int nrows = min(MM1_ROWS, N - rowbase);

    for (int i = t; i < NUM_FEAT * HIDDEN; i += 256) sw[i] = W1[i];

    for (int i = t; i < nrows * 32; i += 256) {
        int r = i >> 5, q = i & 31;
        float4 v = ((const float4*)(x + (size_t)(rowbase + r) * NUM_FEAT))[q];
        sx[r][q * 4 + 0] = v.x; sx[r][q * 4 + 1] = v.y;
        sx[r][q * 4 + 2] = v.z; sx[r][q * 4 + 3] = v.w;
    }
    __syncthreads();

    const int r  = t >> 2;          // 0..63
    const int c0 = (t & 3) * 4;     // 0,4,8,12
    if (r < nrows) {
        float a0 = 0.f, a1 = 0.f, a2 = 0.f, a3 = 0.f;
        #pragma unroll 8
        for (int k = 0; k < NUM_FEAT; ++k) {
            float xv = sx[r][k];
            const float* wr = &sw[k * HIDDEN + c0];
            a0 += xv * wr[0]; a1 += xv * wr[1];
            a2 += xv * wr[2]; a3 += xv * wr[3];
        }
        float4 o = {a0, a1, a2, a3};
        ((float4*)(y + (size_t)(rowbase + r) * HIDDEN))[t & 3] = o;
    }
}

// ---------------- K2: agg[dst] += y[src]  (4 threads per edge) ----------------
__global__ __launch_bounds__(256) void k_scatter(const int* __restrict__ ei,
                                                 const float* __restrict__ y,
                                                 float* __restrict__ agg, int E) {
    int t = blockIdx.x * 256 + threadIdx.x;
    int e = t >> 2, p = t & 3;
    if (e >= E) return;
    int s = ei[e];
    int d = ei[E + e];
    float4 v = ((const float4*)(y + (size_t)s * HIDDEN))[p];
    float* dp = agg + (size_t)d * HIDDEN + p * 4;
    atomicAdd(dp + 0, v.x);
    atomicAdd(dp + 1, v.y);
    atomicAdd(dp + 2, v.z);
    atomicAdd(dp + 3, v.w);
}

// ---------------- K3: A := relu(A + B + b1) @ W2   (fused, in-place per node) ----
__global__ __launch_bounds__(256) void k_l2fused(float* __restrict__ A,
                                                 const float* __restrict__ B,
                                                 const float* __restrict__ bias,
                                                 const float* __restrict__ W2,
                                                 int N) {
    __shared__ float sw[HIDDEN * HIDDEN];
    int t = threadIdx.x;
    if (t < HIDDEN * HIDDEN) sw[t] = W2[t];
    __syncthreads();
    int n = blockIdx.x * 256 + t;
    if (n >= N) return;
    float h[HIDDEN];
    const float4* ap = (const float4*)(A + (size_t)n * HIDDEN);
    const float4* bp = (const float4*)(B + (size_t)n * HIDDEN);
    #pragma unroll
    for (int q = 0; q < 4; ++q) {
        float4 a = ap[q];
        float4 b = bp[q];
        float4 bv = ((const float4*)bias)[q];
        h[q * 4 + 0] = fmaxf(a.x + b.x + bv.x, 0.f);
        h[q * 4 + 1] = fmaxf(a.y + b.y + bv.y, 0.f);
        h[q * 4 + 2] = fmaxf(a.z + b.z + bv.z, 0.f);
        h[q * 4 + 3] = fmaxf(a.w + b.w + bv.w, 0.f);
    }
    float acc[HIDDEN];
    #pragma unroll
    for (int c = 0; c < HIDDEN; ++c) acc[c] = 0.f;
    #pragma unroll
    for (int k = 0; k < HIDDEN; ++k) {
        float hk = h[k];
        #pragma unroll
        for (int c = 0; c < HIDDEN; ++c) acc[c] += hk * sw[k * HIDDEN + c];
    }
    float4* yp = (float4*)(A + (size_t)n * HIDDEN);
    #pragma unroll
    for (int q = 0; q < 4; ++q) {
        float4 o = {acc[q * 4 + 0], acc[q * 4 + 1], acc[q * 4 + 2], acc[q * 4 + 3]};
        yp[q] = o;
    }
}

// ---------------- K4: hierarchical pool: wave shfl-reduce -> LDS -> global ----
// batch is SORTED, so a wave's 16 nodes are nearly always one graph.
#define POOL_BLOCKS 512
__global__ __launch_bounds__(256) void k_pool2(const float* __restrict__ A,
                                               const float* __restrict__ B,
                                               const float* __restrict__ bias,
                                               const int* __restrict__ batch,
                                               float* __restrict__ sums,
                                               float* __restrict__ counts,
                                               int N, int chunk) {
    __shared__ float ssum[NUM_GRAPHS * HIDDEN];   // 8 KB
    __shared__ float scnt[NUM_GRAPHS];
    const int t = threadIdx.x;
    for (int i = t; i < NUM_GRAPHS * HIDDEN; i += 256) ssum[i] = 0.f;
    if (t < NUM_GRAPHS) scnt[t] = 0.f;
    __syncthreads();

    const int n0 = blockIdx.x * chunk;
    const int n1 = min(n0 + chunk, N);
    const int lane = t & 63;
    const int p = t & 3;
    const float4 bv = ((const float4*)bias)[p];

    for (int nb = n0; nb < n1; nb += 64) {
        int n = nb + (t >> 2);
        bool active = (n < n1);
        int nc = active ? n : (n1 - 1);     // clamp so every lane has a valid g
        int g = batch[nc];
        float4 h = {0.f, 0.f, 0.f, 0.f};
        if (active) {
            float4 a = ((const float4*)(A + (size_t)n * HIDDEN))[p];
            float4 b = ((const float4*)(B + (size_t)n * HIDDEN))[p];
            h.x = fmaxf(a.x + b.x + bv.x, 0.f);
            h.y = fmaxf(a.y + b.y + bv.y, 0.f);
            h.z = fmaxf(a.z + b.z + bv.z, 0.f);
            h.w = fmaxf(a.w + b.w + bv.w, 0.f);
        }
        int gf = __builtin_amdgcn_readfirstlane(g);
        bool uniform = (__ballot(g == gf) == ~0ull);
        if (uniform) {
            // reduce the 16 node-groups of this wave (lane strides 4,8,16,32)
            #pragma unroll
            for (int m = 4; m <= 32; m <<= 1) {
                h.x += __shfl_xor(h.x, m, 64);
                h.y += __shfl_xor(h.y, m, 64);
                h.z += __shfl_xor(h.z, m, 64);
                h.w += __shfl_xor(h.w, m, 64);
            }
            if (lane < 4) {
                float* sp = &ssum[gf * HIDDEN + p * 4];
                atomicAdd(sp + 0, h.x);
                atomicAdd(sp + 1, h.y);
                atomicAdd(sp + 2, h.z);
                atomicAdd(sp + 3, h.w);
            }
            if (lane == 0) {
                int wfirst = nb + ((t >> 6) << 4);
                int cnt = min(16, n1 - wfirst);
                if (cnt > 0) atomicAdd(&scnt[gf], (float)cnt);
            }
        } else if (active) {
            float* sp = &ssum[g * HIDDEN + p * 4];
            atomicAdd(sp + 0, h.x);
            atomicAdd(sp + 1, h.y);
            atomicAdd(sp + 2, h.z);
            atomicAdd(sp + 3, h.w);
            if (p == 0) atomicAdd(&scnt[g], 1.f);
        }
    }
    __syncthreads();
    for (int i = t; i < NUM_GRAPHS * HIDDEN; i += 256) {
        float v = ssum[i];
        if (v != 0.f) atomicAdd(&sums[i], v);
    }
    if (t < NUM_GRAPHS) {
        float v = scnt[t];
        if (v != 0.f) atomicAdd(&counts[t], v);
    }
}

// ---------------- K5: out = (sums/counts) @ Wfc + bfc ----------------
__global__ __launch_bounds__(256) void k_fc(const float* __restrict__ sums,
                                            const float* __restrict__ counts,
                                            const float* __restrict__ Wfc,
                                            const float* __restrict__ bfc,
                                            float* __restrict__ out) {
    int t = blockIdx.x * 256 + threadIdx.x;
    if (t >= NUM_GRAPHS * NUM_CLS) return;
    int g = t / NUM_CLS, c = t % NUM_CLS;
    float inv = 1.0f / fmaxf(counts[g], 1.0f);
    float acc = bfc[c];
    #pragma unroll
    for (int k = 0; k < HIDDEN; ++k)
        acc += (sums[g * HIDDEN + k] * inv) * Wfc[k * NUM_CLS + c];
    out[t] = acc;
}

extern "C" void kernel_launch(void* const* d_in, const int* in_sizes, int n_in,
                              void* d_out, int out_size, void* d_ws, size_t ws_size,
                              hipStream_t stream) {
    const float* x    = (const float*)d_in[0];
    const int*   ei   = (const int*)d_in[1];   // [2, E] (src row then dst row)
    const int*   batch= (const int*)d_in[2];
    const float* W1   = (const float*)d_in[3];
    const float* b1   = (const float*)d_in[4];
    const float* W2   = (const float*)d_in[5];
    const float* b2   = (const float*)d_in[6];
    const float* Wfc  = (const float*)d_in[7];
    const float* bfc  = (const float*)d_in[8];
    float* out = (float*)d_out;

    const size_t NB = (size_t)N_NODES * HIDDEN * sizeof(float);   // 6.4 MB
    char* ws = (char*)d_ws;
    float* A     = (float*)(ws);
    float* B     = (float*)(ws + NB);
    float* sums  = (float*)(ws + 2 * NB);
    float* counts= (float*)(ws + 2 * NB + (size_t)NUM_GRAPHS * HIDDEN * sizeof(float));

    const int gridMM1  = (N_NODES + MM1_ROWS - 1) / MM1_ROWS;
    const int gridScat = (N_EDGES * 4 + 255) / 256;
    const int gridNode = (N_NODES + 255) / 256;
    const int poolChunk = (N_NODES + POOL_BLOCKS - 1) / POOL_BLOCKS;

    hipMemsetAsync(B, 0, NB, stream);
    hipMemsetAsync(sums, 0, (size_t)(NUM_GRAPHS * HIDDEN + NUM_GRAPHS) * sizeof(float), stream);

    // layer 1: A = x@W1 ; B = scatter(A)
    k_mm1<<<gridMM1, 256, 0, stream>>>(x, W1, A, N_NODES);
    k_scatter<<<gridScat, 256, 0, stream>>>(ei, A, B, N_EDGES);

    // layer 2 (fused): A := relu(A+B+b1) @ W2 ; re-zero B ; B = scatter(A)
    k_l2fused<<<gridNode, 256, 0, stream>>>(A, B, b1, W2, N_NODES);
    hipMemsetAsync(B, 0, NB, stream);
    k_scatter<<<gridScat, 256, 0, stream>>>(ei, A, B, N_EDGES);

    // pool(relu(A+B+b2)) -> sums/counts ; FC head
    k_pool2<<<POOL_BLOCKS, 256, 0, stream>>>(A, B, b2, batch, sums, counts,
                                             N_NODES, poolChunk);
    k_fc<<<(NUM_GRAPHS * NUM_CLS + 255) / 256, 256, 0, stream>>>(sums, counts, Wfc, bfc, out);
}

// Round 3
// 153.000 us; speedup vs baseline: 5.0853x; 2.0868x over previous
//
#include <hip/hip_runtime.h>
#include <hip/hip_bf16.h>

// Problem sizes (fixed by reference)
#define N_NODES   100000
#define N_EDGES   640000
#define NUM_GRAPHS 128
#define NUM_FEAT  128
#define HIDDEN    16
#define NUM_CLS   10

// ---------------- K1: y = x @ W1   [N,128] @ [128,16] -> [N,16] ----------------
#define MM1_ROWS 64
__global__ __launch_bounds__(256) void k_mm1(const float* __restrict__ x,
                                             const float* __restrict__ W1,
                                             float* __restrict__ y, int N) {
    __shared__ float sx[MM1_ROWS][129];
    __shared__ float sw[NUM_FEAT * HIDDEN];
    const int t = threadIdx.x;
    const int rowbase = blockIdx.x * MM1_ROWS;
    const int nrows = min(MM1_ROWS, N - rowbase);

    for (int i = t; i < NUM_FEAT * HIDDEN; i += 256) sw[i] = W1[i];

    for (int i = t; i < nrows * 32; i += 256) {
        int r = i >> 5, q = i & 31;
        float4 v = ((const float4*)(x + (size_t)(rowbase + r) * NUM_FEAT))[q];
        sx[r][q * 4 + 0] = v.x; sx[r][q * 4 + 1] = v.y;
        sx[r][q * 4 + 2] = v.z; sx[r][q * 4 + 3] = v.w;
    }
    __syncthreads();

    const int r  = t >> 2;
    const int c0 = (t & 3) * 4;
    if (r < nrows) {
        float a0 = 0.f, a1 = 0.f, a2 = 0.f, a3 = 0.f;
        #pragma unroll 8
        for (int k = 0; k < NUM_FEAT; ++k) {
            float xv = sx[r][k];
            const float* wr = &sw[k * HIDDEN + c0];
            a0 += xv * wr[0]; a1 += xv * wr[1];
            a2 += xv * wr[2]; a3 += xv * wr[3];
        }
        float4 o = {a0, a1, a2, a3};
        ((float4*)(y + (size_t)(rowbase + r) * HIDDEN))[t & 3] = o;
    }
}

// ---------------- CSR build: hist -> scan -> finalize -> reorder ----------------
__global__ __launch_bounds__(256) void k_hist(const int* __restrict__ ei,
                                              int* __restrict__ deg, int E) {
    int e = blockIdx.x * 256 + threadIdx.x;
    if (e >= E) return;
    atomicAdd(&deg[ei[E + e]], 1);
}

#define SCAN_BLK 256
__global__ __launch_bounds__(SCAN_BLK) void k_scan_a(const int* __restrict__ deg,
                                                     int* __restrict__ excl,
                                                     int* __restrict__ bsum, int N) {
    __shared__ int s[SCAN_BLK];
    int t = threadIdx.x;
    int i = blockIdx.x * SCAN_BLK + t;
    int v = (i < N) ? deg[i] : 0;
    s[t] = v;
    __syncthreads();
    for (int off = 1; off < SCAN_BLK; off <<= 1) {
        int add = (t >= off) ? s[t - off] : 0;
        __syncthreads();
        s[t] += add;
        __syncthreads();
    }
    if (i < N) excl[i] = s[t] - v;            // exclusive within block
    if (t == SCAN_BLK - 1) bsum[blockIdx.x] = s[t];
}

__global__ __launch_bounds__(512) void k_scan_b(int* __restrict__ bsum, int nb) {
    __shared__ int s[512];
    int t = threadIdx.x;
    int v = (t < nb) ? bsum[t] : 0;
    s[t] = v;
    __syncthreads();
    for (int off = 1; off < 512; off <<= 1) {
        int add = (t >= off) ? s[t - off] : 0;
        __syncthreads();
        s[t] += add;
        __syncthreads();
    }
    if (t < nb) bsum[t] = s[t] - v;           // exclusive block offsets
}

__global__ __launch_bounds__(256) void k_finalize(const int* __restrict__ excl,
                                                  const int* __restrict__ bsum,
                                                  int* __restrict__ row,
                                                  int* __restrict__ cursor, int N) {
    int i = blockIdx.x * 256 + threadIdx.x;
    if (i >= N) return;
    int r = excl[i] + bsum[i / SCAN_BLK];
    row[i] = r;
    cursor[i] = r;
}

__global__ __launch_bounds__(256) void k_reorder(const int* __restrict__ ei,
                                                 int* __restrict__ cursor,
                                                 int* __restrict__ srcidx, int E) {
    int e = blockIdx.x * 256 + threadIdx.x;
    if (e >= E) return;
    int s = ei[e];
    int d = ei[E + e];
    int slot = atomicAdd(&cursor[d], 1);
    srcidx[slot] = s;
}

// ---------------- gather: B[n] = sum_{e in CSR[n]} A[src[e]]  (no atomics) ------
__global__ __launch_bounds__(256) void k_gather(const int* __restrict__ row,
                                                const int* __restrict__ deg,
                                                const int* __restrict__ srcidx,
                                                const float* __restrict__ A,
                                                float* __restrict__ B, int N) {
    int t = blockIdx.x * 256 + threadIdx.x;
    int n = t >> 2, p = t & 3;
    if (n >= N) return;
    int r0 = row[n];
    int d  = deg[n];
    float4 acc = {0.f, 0.f, 0.f, 0.f};
    for (int i = 0; i < d; ++i) {
        int s = srcidx[r0 + i];
        float4 v = ((const float4*)(A + (size_t)s * HIDDEN))[p];
        acc.x += v.x; acc.y += v.y; acc.z += v.z; acc.w += v.w;
    }
    ((float4*)(B + (size_t)n * HIDDEN))[p] = acc;
}

// ---------------- A := relu(A + B + b1) @ W2   (fused, in-place per node) -------
__global__ __launch_bounds__(256) void k_l2fused(float* __restrict__ A,
                                                 const float* __restrict__ B,
                                                 const float* __restrict__ bias,
                                                 const float* __restrict__ W2,
                                                 int N) {
    __shared__ float sw[HIDDEN * HIDDEN];
    int t = threadIdx.x;
    if (t < HIDDEN * HIDDEN) sw[t] = W2[t];
    __syncthreads();
    int n = blockIdx.x * 256 + t;
    if (n >= N) return;
    float h[HIDDEN];
    const float4* ap = (const float4*)(A + (size_t)n * HIDDEN);
    const float4* bp = (const float4*)(B + (size_t)n * HIDDEN);
    #pragma unroll
    for (int q = 0; q < 4; ++q) {
        float4 a = ap[q];
        float4 b = bp[q];
        float4 bv = ((const float4*)bias)[q];
        h[q * 4 + 0] = fmaxf(a.x + b.x + bv.x, 0.f);
        h[q * 4 + 1] = fmaxf(a.y + b.y + bv.y, 0.f);
        h[q * 4 + 2] = fmaxf(a.z + b.z + bv.z, 0.f);
        h[q * 4 + 3] = fmaxf(a.w + b.w + bv.w, 0.f);
    }
    float acc[HIDDEN];
    #pragma unroll
    for (int c = 0; c < HIDDEN; ++c) acc[c] = 0.f;
    #pragma unroll
    for (int k = 0; k < HIDDEN; ++k) {
        float hk = h[k];
        #pragma unroll
        for (int c = 0; c < HIDDEN; ++c) acc[c] += hk * sw[k * HIDDEN + c];
    }
    float4* yp = (float4*)(A + (size_t)n * HIDDEN);
    #pragma unroll
    for (int q = 0; q < 4; ++q) {
        float4 o = {acc[q * 4 + 0], acc[q * 4 + 1], acc[q * 4 + 2], acc[q * 4 + 3]};
        yp[q] = o;
    }
}

// ---------------- hierarchical pool (batch sorted) ------------------------------
#define POOL_BLOCKS 512
__global__ __launch_bounds__(256) void k_pool2(const float* __restrict__ A,
                                               const float* __restrict__ B,
                                               const float* __restrict__ bias,
                                               const int* __restrict__ batch,
                                               float* __restrict__ sums,
                                               float* __restrict__ counts,
                                               int N, int chunk) {
    __shared__ float ssum[NUM_GRAPHS * HIDDEN];
    __shared__ float scnt[NUM_GRAPHS];
    const int t = threadIdx.x;
    for (int i = t; i < NUM_GRAPHS * HIDDEN; i += 256) ssum[i] = 0.f;
    if (t < NUM_GRAPHS) scnt[t] = 0.f;
    __syncthreads();

    const int n0 = blockIdx.x * chunk;
    const int n1 = min(n0 + chunk, N);
    const int lane = t & 63;
    const int p = t & 3;
    const float4 bv = ((const float4*)bias)[p];

    for (int nb = n0; nb < n1; nb += 64) {
        int n = nb + (t >> 2);
        bool active = (n < n1);
        int nc = active ? n : (n1 - 1);
        int g = batch[nc];
        float4 h = {0.f, 0.f, 0.f, 0.f};
        if (active) {
            float4 a = ((const float4*)(A + (size_t)n * HIDDEN))[p];
            float4 b = ((const float4*)(B + (size_t)n * HIDDEN))[p];
            h.x = fmaxf(a.x + b.x + bv.x, 0.f);
            h.y = fmaxf(a.y + b.y + bv.y, 0.f);
            h.z = fmaxf(a.z + b.z + bv.z, 0.f);
            h.w = fmaxf(a.w + b.w + bv.w, 0.f);
        }
        int gf = __builtin_amdgcn_readfirstlane(g);
        bool uniform = (__ballot(g == gf) == ~0ull);
        if (uniform) {
            #pragma unroll
            for (int m = 4; m <= 32; m <<= 1) {
                h.x += __shfl_xor(h.x, m, 64);
                h.y += __shfl_xor(h.y, m, 64);
                h.z += __shfl_xor(h.z, m, 64);
                h.w += __shfl_xor(h.w, m, 64);
            }
            if (lane < 4) {
                float* sp = &ssum[gf * HIDDEN + p * 4];
                atomicAdd(sp + 0, h.x);
                atomicAdd(sp + 1, h.y);
                atomicAdd(sp + 2, h.z);
                atomicAdd(sp + 3, h.w);
            }
            if (lane == 0) {
                int wfirst = nb + ((t >> 6) << 4);
                int cnt = min(16, n1 - wfirst);
                if (cnt > 0) atomicAdd(&scnt[gf], (float)cnt);
            }
        } else if (active) {
            float* sp = &ssum[g * HIDDEN + p * 4];
            atomicAdd(sp + 0, h.x);
            atomicAdd(sp + 1, h.y);
            atomicAdd(sp + 2, h.z);
            atomicAdd(sp + 3, h.w);
            if (p == 0) atomicAdd(&scnt[g], 1.f);
        }
    }
    __syncthreads();
    for (int i = t; i < NUM_GRAPHS * HIDDEN; i += 256) {
        float v = ssum[i];
        if (v != 0.f) atomicAdd(&sums[i], v);
    }
    if (t < NUM_GRAPHS) {
        float v = scnt[t];
        if (v != 0.f) atomicAdd(&counts[t], v);
    }
}

// ---------------- FC head ------------------------------------------------------
__global__ __launch_bounds__(256) void k_fc(const float* __restrict__ sums,
                                            const float* __restrict__ counts,
                                            const float* __restrict__ Wfc,
                                            const float* __restrict__ bfc,
                                            float* __restrict__ out) {
    int t = blockIdx.x * 256 + threadIdx.x;
    if (t >= NUM_GRAPHS * NUM_CLS) return;
    int g = t / NUM_CLS, c = t % NUM_CLS;
    float inv = 1.0f / fmaxf(counts[g], 1.0f);
    float acc = bfc[c];
    #pragma unroll
    for (int k = 0; k < HIDDEN; ++k)
        acc += (sums[g * HIDDEN + k] * inv) * Wfc[k * NUM_CLS + c];
    out[t] = acc;
}

extern "C" void kernel_launch(void* const* d_in, const int* in_sizes, int n_in,
                              void* d_out, int out_size, void* d_ws, size_t ws_size,
                              hipStream_t stream) {
    const float* x    = (const float*)d_in[0];
    const int*   ei   = (const int*)d_in[1];   // [2, E] (src row then dst row)
    const int*   batch= (const int*)d_in[2];
    const float* W1   = (const float*)d_in[3];
    const float* b1   = (const float*)d_in[4];
    const float* W2   = (const float*)d_in[5];
    const float* b2   = (const float*)d_in[6];
    const float* Wfc  = (const float*)d_in[7];
    const float* bfc  = (const float*)d_in[8];
    float* out = (float*)d_out;

    const size_t NB = (size_t)N_NODES * HIDDEN * sizeof(float);       // 6.4 MB
    const size_t NI = (size_t)N_NODES * sizeof(int);                  // 400 KB
    const int nScanBlocks = (N_NODES + SCAN_BLK - 1) / SCAN_BLK;      // 391

    char* ws = (char*)d_ws;
    size_t off = 0;
    float* A      = (float*)(ws + off); off += NB;
    float* B      = (float*)(ws + off); off += NB;
    float* sums   = (float*)(ws + off); off += (size_t)NUM_GRAPHS * HIDDEN * sizeof(float);
    float* counts = (float*)(ws + off); off += (size_t)NUM_GRAPHS * sizeof(float);
    int* deg    = (int*)(ws + off); off += NI;
    int* excl   = (int*)(ws + off); off += NI;
    int* row    = (int*)(ws + off); off += NI;
    int* cursor = (int*)(ws + off); off += NI;
    int* bsum   = (int*)(ws + off); off += (size_t)nScanBlocks * sizeof(int);
    // align to 16
    off = (off + 15) & ~(size_t)15;
    int* srcidx = (int*)(ws + off); off += (size_t)N_EDGES * sizeof(int);

    const int gridMM1  = (N_NODES + MM1_ROWS - 1) / MM1_ROWS;
    const int gridEdge = (N_EDGES + 255) / 256;
    const int gridNode = (N_NODES + 255) / 256;
    const int gridN4   = (N_NODES * 4 + 255) / 256;
    const int poolChunk = (N_NODES + POOL_BLOCKS - 1) / POOL_BLOCKS;

    hipMemsetAsync(deg, 0, NI, stream);
    hipMemsetAsync(sums, 0, (size_t)(NUM_GRAPHS * HIDDEN + NUM_GRAPHS) * sizeof(float), stream);

    // CSR build (shared by both layers) — overlaps with mm1 on same stream order
    k_mm1<<<gridMM1, 256, 0, stream>>>(x, W1, A, N_NODES);
    k_hist<<<gridEdge, 256, 0, stream>>>(ei, deg, N_EDGES);
    k_scan_a<<<nScanBlocks, SCAN_BLK, 0, stream>>>(deg, excl, bsum, N_NODES);
    k_scan_b<<<1, 512, 0, stream>>>(bsum, nScanBlocks);
    k_finalize<<<gridNode, 256, 0, stream>>>(excl, bsum, row, cursor, N_NODES);
    k_reorder<<<gridEdge, 256, 0, stream>>>(ei, cursor, srcidx, N_EDGES);

    // layer 1: B = gather(A)
    k_gather<<<gridN4, 256, 0, stream>>>(row, deg, srcidx, A, B, N_NODES);

    // layer 2 (fused): A := relu(A+B+b1) @ W2 ; B = gather(A)
    k_l2fused<<<gridNode, 256, 0, stream>>>(A, B, b1, W2, N_NODES);
    k_gather<<<gridN4, 256, 0, stream>>>(row, deg, srcidx, A, B, N_NODES);

    // pool(relu(A+B+b2)) -> sums/counts ; FC head
    k_pool2<<<POOL_BLOCKS, 256, 0, stream>>>(A, B, b2, batch, sums, counts,
                                             N_NODES, poolChunk);
    k_fc<<<(NUM_GRAPHS * NUM_CLS + 255) / 256, 256, 0, stream>>>(sums, counts, Wfc, bfc, out);
}

// Round 4
// 113.336 us; speedup vs baseline: 6.8650x; 1.3500x over previous
//
#include <hip/hip_runtime.h>
#include <hip/hip_bf16.h>

// Problem sizes (fixed by reference)
#define N_NODES   100000
#define N_EDGES   640000
#define NUM_GRAPHS 128
#define NUM_FEAT  128
#define HIDDEN    16
#define NUM_CLS   10

// Bucket sort params
#define NBLK   256            // blocks in P1/P3
#define EPB    (N_EDGES / NBLK)   // 2500 edges per block (exact)
#define NBUCK  256            // dst >> 9 -> 196 used buckets
#define BSHIFT 9
#define BNODES 512            // nodes per bucket

// ---------------- K1: y = x @ W1   [N,128] @ [128,16] -> [N,16] ----------------
#define MM1_ROWS 64
__global__ __launch_bounds__(256) void k_mm1(const float* __restrict__ x,
                                             const float* __restrict__ W1,
                                             float* __restrict__ y, int N) {
    __shared__ float sx[MM1_ROWS][132];   // stride 132: float4-aligned, 2-way-bank max
    __shared__ float sw[NUM_FEAT * HIDDEN];
    const int t = threadIdx.x;
    const int rowbase = blockIdx.x * MM1_ROWS;
    const int nrows = min(MM1_ROWS, N - rowbase);

    for (int i = t; i < NUM_FEAT * HIDDEN; i += 256) sw[i] = W1[i];

    for (int i = t; i < nrows * 32; i += 256) {
        int r = i >> 5, q = i & 31;
        float4 v = ((const float4*)(x + (size_t)(rowbase + r) * NUM_FEAT))[q];
        *(float4*)&sx[r][q * 4] = v;
    }
    __syncthreads();

    const int r  = t >> 2;
    const int c0 = (t & 3) * 4;
    if (r < nrows) {
        float4 o = {0.f, 0.f, 0.f, 0.f};
        #pragma unroll 4
        for (int k4 = 0; k4 < 32; ++k4) {
            float4 xv = *(const float4*)&sx[r][k4 * 4];
            const float* wb = &sw[(k4 * 4) * HIDDEN + c0];
            float4 w0 = *(const float4*)(wb);
            float4 w1 = *(const float4*)(wb + HIDDEN);
            float4 w2 = *(const float4*)(wb + 2 * HIDDEN);
            float4 w3 = *(const float4*)(wb + 3 * HIDDEN);
            o.x += xv.x * w0.x + xv.y * w1.x + xv.z * w2.x + xv.w * w3.x;
            o.y += xv.x * w0.y + xv.y * w1.y + xv.z * w2.y + xv.w * w3.y;
            o.z += xv.x * w0.z + xv.y * w1.z + xv.z * w2.z + xv.w * w3.z;
            o.w += xv.x * w0.w + xv.y * w1.w + xv.z * w2.w + xv.w * w3.w;
        }
        ((float4*)(y + (size_t)(rowbase + r) * HIDDEN))[t & 3] = o;
    }
}

// ---------------- P1: per-block bucket histogram (LDS only) --------------------
__global__ __launch_bounds__(256) void k_bcount(const int* __restrict__ ei,
                                                int* __restrict__ cnt /*[NBUCK][NBLK]*/) {
    __shared__ int h[NBUCK];
    const int t = threadIdx.x, b = blockIdx.x;
    h[t] = 0;
    __syncthreads();
    const int e0 = b * EPB, e1 = e0 + EPB;
    for (int e = e0 + t; e < e1; e += 256)
        atomicAdd(&h[ei[N_EDGES + e] >> BSHIFT], 1);
    __syncthreads();
    cnt[t * NBLK + b] = h[t];   // bucket-major layout for the scan
}

// ---------------- P2: exclusive scan of 65536 counts; zero sums ----------------
__global__ __launch_bounds__(1024) void k_scan(int* __restrict__ c,
                                               float* __restrict__ sums /*2304 fl*/) {
    __shared__ int s[1024];
    const int t = threadIdx.x;
    for (int i = t; i < NUM_GRAPHS * HIDDEN + NUM_GRAPHS; i += 1024) sums[i] = 0.f;
    const int i0 = t * 64;
    int sum = 0;
    for (int i = 0; i < 64; ++i) sum += c[i0 + i];
    s[t] = sum;
    __syncthreads();
    for (int off = 1; off < 1024; off <<= 1) {
        int add = (t >= off) ? s[t - off] : 0;
        __syncthreads();
        s[t] += add;
        __syncthreads();
    }
    int run = s[t] - sum;            // exclusive prefix of this segment
    for (int i = 0; i < 64; ++i) {
        int v = c[i0 + i];
        c[i0 + i] = run;
        run += v;
    }
}

// ---------------- P3: place edges into bucket regions (LDS cursors) ------------
__global__ __launch_bounds__(256) void k_place(const int* __restrict__ ei,
                                               const int* __restrict__ base,
                                               unsigned* __restrict__ packed) {
    __shared__ int cur[NBUCK];
    const int t = threadIdx.x, b = blockIdx.x;
    cur[t] = base[t * NBLK + b];
    __syncthreads();
    const int e0 = b * EPB, e1 = e0 + EPB;
    for (int e = e0 + t; e < e1; e += 256) {
        int srcv = ei[e];
        int dstv = ei[N_EDGES + e];
        int k = dstv >> BSHIFT;
        int slot = atomicAdd(&cur[k], 1);                 // LDS atomic
        packed[slot] = ((unsigned)(dstv & (BNODES - 1)) << 17) | (unsigned)srcv;
    }
}

// ---------------- P4: per-bucket: row[] + srcidx[] (LDS hist/scan/cursor) ------
__global__ __launch_bounds__(256) void k_build(const unsigned* __restrict__ packed,
                                               const int* __restrict__ base,
                                               int* __restrict__ row,
                                               int* __restrict__ srcidx) {
    __shared__ int h[BNODES];
    __shared__ int ps[256];
    __shared__ int e2[BNODES];
    __shared__ int cur[BNODES];
    const int k = blockIdx.x, t = threadIdx.x;
    const int s0 = base[k * NBLK];
    const int s1 = (k == NBUCK - 1) ? N_EDGES : base[(k + 1) * NBLK];
    h[t] = 0; h[t + 256] = 0;
    __syncthreads();
    for (int i = s0 + t; i < s1; i += 256)
        atomicAdd(&h[packed[i] >> 17], 1);
    __syncthreads();
    int pv = h[2 * t] + h[2 * t + 1];
    ps[t] = pv;
    __syncthreads();
    for (int off = 1; off < 256; off <<= 1) {
        int add = (t >= off) ? ps[t - off] : 0;
        __syncthreads();
        ps[t] += add;
        __syncthreads();
    }
    int ex = ps[t] - pv;
    e2[2 * t] = ex;               e2[2 * t + 1] = ex + h[2 * t];
    cur[2 * t] = ex;              cur[2 * t + 1] = ex + h[2 * t];
    __syncthreads();
    #pragma unroll
    for (int jj = 0; jj < 2; ++jj) {
        int j = t + jj * 256;
        int node = (k << BSHIFT) + j;
        if (node <= N_NODES) row[node] = s0 + e2[j];   // row[N] sentinel = E
    }
    __syncthreads();
    for (int i = s0 + t; i < s1; i += 256) {
        unsigned p = packed[i];
        int dl = p >> 17;
        int slot = atomicAdd(&cur[dl], 1);             // LDS atomic
        srcidx[s0 + slot] = (int)(p & 0x1FFFFu);
    }
}

// ---- g1f: B[n] = relu(A[n] + sum A[src] + b1) @ W2   (gather + GIN fused) -----
__global__ __launch_bounds__(256) void k_g1f(const int* __restrict__ row,
                                             const int* __restrict__ srcidx,
                                             const float* __restrict__ A,
                                             const float* __restrict__ bias,
                                             const float* __restrict__ W2,
                                             float* __restrict__ B, int N) {
    __shared__ float sw[HIDDEN * HIDDEN];
    const int t = threadIdx.x;
    if (t < HIDDEN * HIDDEN) sw[t] = W2[t];
    __syncthreads();
    const int n = blockIdx.x * 64 + (t >> 2);
    const int p = t & 3;
    if (n >= N) return;
    const int r0 = row[n];
    const int d  = row[n + 1] - r0;
    float4 acc = ((const float4*)(A + (size_t)n * HIDDEN))[p];
    for (int i = 0; i < d; ++i) {
        int s = srcidx[r0 + i];
        float4 v = ((const float4*)(A + (size_t)s * HIDDEN))[p];
        acc.x += v.x; acc.y += v.y; acc.z += v.z; acc.w += v.w;
    }
    const float4 bv = ((const float4*)bias)[p];
    acc.x = fmaxf(acc.x + bv.x, 0.f);
    acc.y = fmaxf(acc.y + bv.y, 0.f);
    acc.z = fmaxf(acc.z + bv.z, 0.f);
    acc.w = fmaxf(acc.w + bv.w, 0.f);
    // h(16) @ W2 -> this thread's 4 output cols; exchange h quads via shfl
    const int lane = t & 63;
    const int qbase = lane & ~3;
    const int c0 = p * 4;
    float4 o = {0.f, 0.f, 0.f, 0.f};
    #pragma unroll
    for (int q = 0; q < 4; ++q) {
        float hx = __shfl(acc.x, qbase + q, 64);
        float hy = __shfl(acc.y, qbase + q, 64);
        float hz = __shfl(acc.z, qbase + q, 64);
        float hw = __shfl(acc.w, qbase + q, 64);
        const float* wb = &sw[(q * 4) * HIDDEN + c0];
        float4 w0 = *(const float4*)(wb);
        float4 w1 = *(const float4*)(wb + HIDDEN);
        float4 w2 = *(const float4*)(wb + 2 * HIDDEN);
        float4 w3 = *(const float4*)(wb + 3 * HIDDEN);
        o.x += hx * w0.x + hy * w1.x + hz * w2.x + hw * w3.x;
        o.y += hx * w0.y + hy * w1.y + hz * w2.y + hw * w3.y;
        o.z += hx * w0.z + hy * w1.z + hz * w2.z + hw * w3.z;
        o.w += hx * w0.w + hy * w1.w + hz * w2.w + hw * w3.w;
    }
    ((float4*)(B + (size_t)n * HIDDEN))[p] = o;
}

// ---- g2p: pool(relu(B[n] + sum B[src] + b2)) -> sums/counts (gather fused) ----
#define POOL_BLOCKS 1024
__global__ __launch_bounds__(256) void k_g2p(const int* __restrict__ row,
                                             const int* __restrict__ srcidx,
                                             const float* __restrict__ B,
                                             const float* __restrict__ bias,
                                             const int* __restrict__ batch,
                                             float* __restrict__ sums,
                                             float* __restrict__ counts,
                                             int N, int chunk) {
    __shared__ float ssum[NUM_GRAPHS * HIDDEN];
    __shared__ float scnt[NUM_GRAPHS];
    const int t = threadIdx.x;
    for (int i = t; i < NUM_GRAPHS * HIDDEN; i += 256) ssum[i] = 0.f;
    if (t < NUM_GRAPHS) scnt[t] = 0.f;
    __syncthreads();

    const int n0 = blockIdx.x * chunk;
    const int n1 = min(n0 + chunk, N);
    const int lane = t & 63;
    const int p = t & 3;
    const float4 bv = ((const float4*)bias)[p];

    for (int nb = n0; nb < n1; nb += 64) {
        int n = nb + (t >> 2);
        bool active = (n < n1);
        int nc = active ? n : (n1 - 1);
        int g = batch[nc];
        float4 h = {0.f, 0.f, 0.f, 0.f};
        if (active) {
            int r0 = row[n];
            int d  = row[n + 1] - r0;
            h = ((const float4*)(B + (size_t)n * HIDDEN))[p];
            for (int i = 0; i < d; ++i) {
                int s = srcidx[r0 + i];
                float4 v = ((const float4*)(B + (size_t)s * HIDDEN))[p];
                h.x += v.x; h.y += v.y; h.z += v.z; h.w += v.w;
            }
            h.x = fmaxf(h.x + bv.x, 0.f);
            h.y = fmaxf(h.y + bv.y, 0.f);
            h.z = fmaxf(h.z + bv.z, 0.f);
            h.w = fmaxf(h.w + bv.w, 0.f);
        }
        int gf = __builtin_amdgcn_readfirstlane(g);
        bool uniform = (__ballot(g == gf) == ~0ull);
        if (uniform) {
            #pragma unroll
            for (int m = 4; m <= 32; m <<= 1) {
                h.x += __shfl_xor(h.x, m, 64);
                h.y += __shfl_xor(h.y, m, 64);
                h.z += __shfl_xor(h.z, m, 64);
                h.w += __shfl_xor(h.w, m, 64);
            }
            if (lane < 4) {
                float* sp = &ssum[gf * HIDDEN + p * 4];
                atomicAdd(sp + 0, h.x);
                atomicAdd(sp + 1, h.y);
                atomicAdd(sp + 2, h.z);
                atomicAdd(sp + 3, h.w);
            }
            if (lane == 0) {
                int wfirst = nb + ((t >> 6) << 4);
                int cnt = min(16, n1 - wfirst);
                if (cnt > 0) atomicAdd(&scnt[gf], (float)cnt);
            }
        } else if (active) {
            float* sp = &ssum[g * HIDDEN + p * 4];
            atomicAdd(sp + 0, h.x);
            atomicAdd(sp + 1, h.y);
            atomicAdd(sp + 2, h.z);
            atomicAdd(sp + 3, h.w);
            if (p == 0) atomicAdd(&scnt[g], 1.f);
        }
    }
    __syncthreads();
    for (int i = t; i < NUM_GRAPHS * HIDDEN; i += 256) {
        float v = ssum[i];
        if (v != 0.f) atomicAdd(&sums[i], v);
    }
    if (t < NUM_GRAPHS) {
        float v = scnt[t];
        if (v != 0.f) atomicAdd(&counts[t], v);
    }
}

// ---------------- FC head ------------------------------------------------------
__global__ __launch_bounds__(256) void k_fc(const float* __restrict__ sums,
                                            const float* __restrict__ counts,
                                            const float* __restrict__ Wfc,
                                            const float* __restrict__ bfc,
                                            float* __restrict__ out) {
    int t = blockIdx.x * 256 + threadIdx.x;
    if (t >= NUM_GRAPHS * NUM_CLS) return;
    int g = t / NUM_CLS, c = t % NUM_CLS;
    float inv = 1.0f / fmaxf(counts[g], 1.0f);
    float acc = bfc[c];
    #pragma unroll
    for (int k = 0; k < HIDDEN; ++k)
        acc += (sums[g * HIDDEN + k] * inv) * Wfc[k * NUM_CLS + c];
    out[t] = acc;
}

extern "C" void kernel_launch(void* const* d_in, const int* in_sizes, int n_in,
                              void* d_out, int out_size, void* d_ws, size_t ws_size,
                              hipStream_t stream) {
    const float* x    = (const float*)d_in[0];
    const int*   ei   = (const int*)d_in[1];   // [2, E] (src row then dst row)
    const int*   batch= (const int*)d_in[2];
    const float* W1   = (const float*)d_in[3];
    const float* b1   = (const float*)d_in[4];
    const float* W2   = (const float*)d_in[5];
    const float* b2   = (const float*)d_in[6];
    const float* Wfc  = (const float*)d_in[7];
    const float* bfc  = (const float*)d_in[8];
    float* out = (float*)d_out;

    const size_t NB = (size_t)N_NODES * HIDDEN * sizeof(float);   // 6.4 MB
    char* ws = (char*)d_ws;
    size_t off = 0;
    float* A      = (float*)(ws + off); off += NB;
    float* B      = (float*)(ws + off); off += NB;
    float* sums   = (float*)(ws + off); off += (size_t)NUM_GRAPHS * HIDDEN * sizeof(float);
    float* counts = (float*)(ws + off); off += (size_t)NUM_GRAPHS * sizeof(float);
    int* row    = (int*)(ws + off); off += (size_t)(N_NODES + 4) * sizeof(int);
    int* base   = (int*)(ws + off); off += (size_t)NBUCK * NBLK * sizeof(int);
    int* srcidx = (int*)(ws + off); off += (size_t)N_EDGES * sizeof(int);
    // packed edge words alias B: P3 writes / P4 reads them strictly before
    // k_g1f (stream-ordered) overwrites B.
    unsigned* packed = (unsigned*)B;

    const int gridMM1 = (N_NODES + MM1_ROWS - 1) / MM1_ROWS;
    const int gridG1  = (N_NODES + 63) / 64;
    const int poolChunk = (N_NODES + POOL_BLOCKS - 1) / POOL_BLOCKS;

    // GEMM first (independent of CSR build)
    k_mm1<<<gridMM1, 256, 0, stream>>>(x, W1, A, N_NODES);

    // CSR build: zero global atomics, zero memsets
    k_bcount<<<NBLK, 256, 0, stream>>>(ei, base);
    k_scan<<<1, 1024, 0, stream>>>(base, sums);
    k_place<<<NBLK, 256, 0, stream>>>(ei, base, packed);
    k_build<<<NBUCK, 256, 0, stream>>>(packed, base, row, srcidx);

    // layer 1+2 fused: B = relu(A + gather(A) + b1) @ W2
    k_g1f<<<gridG1, 256, 0, stream>>>(row, srcidx, A, b1, W2, B, N_NODES);

    // pool(relu(B + gather(B) + b2)) -> sums/counts ; FC head
    k_g2p<<<POOL_BLOCKS, 256, 0, stream>>>(row, srcidx, B, b2, batch, sums, counts,
                                           N_NODES, poolChunk);
    k_fc<<<(NUM_GRAPHS * NUM_CLS + 255) / 256, 256, 0, stream>>>(sums, counts, Wfc, bfc, out);
}

// Round 5
// 84.718 us; speedup vs baseline: 9.1840x; 1.3378x over previous
//
#include <hip/hip_runtime.h>
#include <hip/hip_bf16.h>

// Problem sizes (fixed by reference)
#define N_NODES   100000
#define N_EDGES   640000
#define NUM_GRAPHS 128
#define NUM_FEAT  128
#define HIDDEN    16
#define NUM_CLS   10

// Bucket sort params
#define NBLK   256                 // edge-chunk blocks in bcount/place
#define EPB    (N_EDGES / NBLK)    // 2500 edges per block (exact)
#define NBUCK  256                 // dst >> 9 -> 196 used buckets
#define BSHIFT 9
#define BNODES 512                 // nodes per bucket

// ---------------- K1: (mm1 role) y = x @ W1  ||  (bcount role) bucket hist -----
#define MM1_ROWS 64
__global__ __launch_bounds__(256) void k_mm1_bcount(const float* __restrict__ x,
                                                    const float* __restrict__ W1,
                                                    float* __restrict__ y,
                                                    const int* __restrict__ ei,
                                                    int* __restrict__ cnt,
                                                    int N, int gridMM1) {
    __shared__ float sx[MM1_ROWS][132];   // also aliased as bcount's histogram
    __shared__ float sw[NUM_FEAT * HIDDEN];
    const int t = threadIdx.x;

    if (blockIdx.x >= gridMM1) {
        // ---- bucket histogram role (LDS atomics only) ----
        int* h = (int*)&sx[0][0];
        const int b = blockIdx.x - gridMM1;
        h[t] = 0;
        __syncthreads();
        const int e0 = b * EPB, e1 = e0 + EPB;
        for (int e = e0 + t; e < e1; e += 256)
            atomicAdd(&h[ei[N_EDGES + e] >> BSHIFT], 1);
        __syncthreads();
        cnt[t * NBLK + b] = h[t];   // bucket-major
        return;
    }

    // ---- mm1 role ----
    const int rowbase = blockIdx.x * MM1_ROWS;
    const int nrows = min(MM1_ROWS, N - rowbase);

    for (int i = t; i < NUM_FEAT * HIDDEN; i += 256) sw[i] = W1[i];

    for (int i = t; i < nrows * 32; i += 256) {
        int r = i >> 5, q = i & 31;
        float4 v = ((const float4*)(x + (size_t)(rowbase + r) * NUM_FEAT))[q];
        *(float4*)&sx[r][q * 4] = v;
    }
    __syncthreads();

    const int r  = t >> 2;
    const int c0 = (t & 3) * 4;
    if (r < nrows) {
        float4 o = {0.f, 0.f, 0.f, 0.f};
        #pragma unroll 4
        for (int k4 = 0; k4 < 32; ++k4) {
            float4 xv = *(const float4*)&sx[r][k4 * 4];
            const float* wb = &sw[(k4 * 4) * HIDDEN + c0];
            float4 w0 = *(const float4*)(wb);
            float4 w1 = *(const float4*)(wb + HIDDEN);
            float4 w2 = *(const float4*)(wb + 2 * HIDDEN);
            float4 w3 = *(const float4*)(wb + 3 * HIDDEN);
            o.x += xv.x * w0.x + xv.y * w1.x + xv.z * w2.x + xv.w * w3.x;
            o.y += xv.x * w0.y + xv.y * w1.y + xv.z * w2.y + xv.w * w3.y;
            o.z += xv.x * w0.z + xv.y * w1.z + xv.z * w2.z + xv.w * w3.z;
            o.w += xv.x * w0.w + xv.y * w1.w + xv.z * w2.w + xv.w * w3.w;
        }
        ((float4*)(y + (size_t)(rowbase + r) * HIDDEN))[t & 3] = o;
    }
}

// ---------------- K2: per-bucket exclusive scan of 256 block-counts ------------
// block k: cnt[k*NBLK + t] -> exclusive partial; btot[k] = bucket total.
// block 0 additionally zeroes sums/counts.
__global__ __launch_bounds__(256) void k_bscan(int* __restrict__ cnt,
                                               int* __restrict__ btot,
                                               float* __restrict__ sums) {
    __shared__ int s[256];
    const int k = blockIdx.x, t = threadIdx.x;
    if (k == 0) {
        for (int i = t; i < NUM_GRAPHS * HIDDEN + NUM_GRAPHS; i += 256) sums[i] = 0.f;
    }
    int v = cnt[k * NBLK + t];
    s[t] = v;
    __syncthreads();
    for (int off = 1; off < 256; off <<= 1) {
        int add = (t >= off) ? s[t - off] : 0;
        __syncthreads();
        s[t] += add;
        __syncthreads();
    }
    cnt[k * NBLK + t] = s[t] - v;          // exclusive within bucket
    if (t == 255) btot[k] = s[t];
}

// ---------------- K3: place edges into bucket regions (LDS cursors) ------------
__global__ __launch_bounds__(256) void k_place(const int* __restrict__ ei,
                                               const int* __restrict__ cnt,
                                               const int* __restrict__ btot,
                                               unsigned* __restrict__ packed) {
    __shared__ int bb[NBUCK];
    __shared__ int cur[NBUCK];
    const int t = threadIdx.x, b = blockIdx.x;
    int v = btot[t];
    bb[t] = v;
    __syncthreads();
    for (int off = 1; off < 256; off <<= 1) {
        int add = (t >= off) ? bb[t - off] : 0;
        __syncthreads();
        bb[t] += add;
        __syncthreads();
    }
    cur[t] = (bb[t] - v) + cnt[t * NBLK + b];   // bucketbase + my block's offset
    __syncthreads();
    const int e0 = b * EPB, e1 = e0 + EPB;
    for (int e = e0 + t; e < e1; e += 256) {
        int srcv = ei[e];
        int dstv = ei[N_EDGES + e];
        int k = dstv >> BSHIFT;
        int slot = atomicAdd(&cur[k], 1);                 // LDS atomic
        packed[slot] = ((unsigned)(dstv & (BNODES - 1)) << 17) | (unsigned)srcv;
    }
}

// ---------------- K4: per-bucket: row[] + srcidx[] (LDS hist/scan/cursor) ------
__global__ __launch_bounds__(256) void k_build(const unsigned* __restrict__ packed,
                                               const int* __restrict__ btot,
                                               int* __restrict__ row,
                                               int* __restrict__ srcidx) {
    __shared__ int bb[NBUCK];
    __shared__ int h[BNODES];
    __shared__ int ps[256];
    __shared__ int e2[BNODES];
    __shared__ int cur[BNODES];
    const int k = blockIdx.x, t = threadIdx.x;

    int v = btot[t];
    bb[t] = v;
    __syncthreads();
    for (int off = 1; off < 256; off <<= 1) {
        int add = (t >= off) ? bb[t - off] : 0;
        __syncthreads();
        bb[t] += add;
        __syncthreads();
    }
    __syncthreads();
    const int s1 = bb[k];
    const int s0 = s1 - btot[k];

    h[t] = 0; h[t + 256] = 0;
    __syncthreads();
    for (int i = s0 + t; i < s1; i += 256)
        atomicAdd(&h[packed[i] >> 17], 1);
    __syncthreads();
    int pv = h[2 * t] + h[2 * t + 1];
    ps[t] = pv;
    __syncthreads();
    for (int off = 1; off < 256; off <<= 1) {
        int add = (t >= off) ? ps[t - off] : 0;
        __syncthreads();
        ps[t] += add;
        __syncthreads();
    }
    int ex = ps[t] - pv;
    e2[2 * t] = ex;               e2[2 * t + 1] = ex + h[2 * t];
    cur[2 * t] = ex;              cur[2 * t + 1] = ex + h[2 * t];
    __syncthreads();
    #pragma unroll
    for (int jj = 0; jj < 2; ++jj) {
        int j = t + jj * 256;
        int node = (k << BSHIFT) + j;
        if (node <= N_NODES) row[node] = s0 + e2[j];   // row[N] sentinel = E
    }
    __syncthreads();
    for (int i = s0 + t; i < s1; i += 256) {
        unsigned p = packed[i];
        int dl = p >> 17;
        int slot = atomicAdd(&cur[dl], 1);             // LDS atomic
        srcidx[s0 + slot] = (int)(p & 0x1FFFFu);
    }
}

// ---- g1f: B[n] = relu(A[n] + sum A[src] + b1) @ W2   (gather + GIN fused) -----
__global__ __launch_bounds__(256) void k_g1f(const int* __restrict__ row,
                                             const int* __restrict__ srcidx,
                                             const float* __restrict__ A,
                                             const float* __restrict__ bias,
                                             const float* __restrict__ W2,
                                             float* __restrict__ B, int N) {
    __shared__ float sw[HIDDEN * HIDDEN];
    const int t = threadIdx.x;
    if (t < HIDDEN * HIDDEN) sw[t] = W2[t];
    __syncthreads();
    const int n = blockIdx.x * 64 + (t >> 2);
    const int p = t & 3;
    if (n >= N) return;
    const int r0 = row[n];
    const int d  = row[n + 1] - r0;
    float4 acc = ((const float4*)(A + (size_t)n * HIDDEN))[p];
    for (int i = 0; i < d; ++i) {
        int s = srcidx[r0 + i];
        float4 v = ((const float4*)(A + (size_t)s * HIDDEN))[p];
        acc.x += v.x; acc.y += v.y; acc.z += v.z; acc.w += v.w;
    }
    const float4 bv = ((const float4*)bias)[p];
    acc.x = fmaxf(acc.x + bv.x, 0.f);
    acc.y = fmaxf(acc.y + bv.y, 0.f);
    acc.z = fmaxf(acc.z + bv.z, 0.f);
    acc.w = fmaxf(acc.w + bv.w, 0.f);
    // h(16) @ W2 -> this thread's 4 output cols; exchange h quads via shfl
    const int lane = t & 63;
    const int qbase = lane & ~3;
    const int c0 = p * 4;
    float4 o = {0.f, 0.f, 0.f, 0.f};
    #pragma unroll
    for (int q = 0; q < 4; ++q) {
        float hx = __shfl(acc.x, qbase + q, 64);
        float hy = __shfl(acc.y, qbase + q, 64);
        float hz = __shfl(acc.z, qbase + q, 64);
        float hw = __shfl(acc.w, qbase + q, 64);
        const float* wb = &sw[(q * 4) * HIDDEN + c0];
        float4 w0 = *(const float4*)(wb);
        float4 w1 = *(const float4*)(wb + HIDDEN);
        float4 w2 = *(const float4*)(wb + 2 * HIDDEN);
        float4 w3 = *(const float4*)(wb + 3 * HIDDEN);
        o.x += hx * w0.x + hy * w1.x + hz * w2.x + hw * w3.x;
        o.y += hx * w0.y + hy * w1.y + hz * w2.y + hw * w3.y;
        o.z += hx * w0.z + hy * w1.z + hz * w2.z + hw * w3.z;
        o.w += hx * w0.w + hy * w1.w + hz * w2.w + hw * w3.w;
    }
    ((float4*)(B + (size_t)n * HIDDEN))[p] = o;
}

// ---- g2p: pool(relu(B[n] + sum B[src] + b2)) -> sums/counts (gather fused) ----
#define POOL_BLOCKS 1024
__global__ __launch_bounds__(256) void k_g2p(const int* __restrict__ row,
                                             const int* __restrict__ srcidx,
                                             const float* __restrict__ B,
                                             const float* __restrict__ bias,
                                             const int* __restrict__ batch,
                                             float* __restrict__ sums,
                                             float* __restrict__ counts,
                                             int N, int chunk) {
    __shared__ float ssum[NUM_GRAPHS * HIDDEN];
    __shared__ float scnt[NUM_GRAPHS];
    const int t = threadIdx.x;
    for (int i = t; i < NUM_GRAPHS * HIDDEN; i += 256) ssum[i] = 0.f;
    if (t < NUM_GRAPHS) scnt[t] = 0.f;
    __syncthreads();

    const int n0 = blockIdx.x * chunk;
    const int n1 = min(n0 + chunk, N);
    const int lane = t & 63;
    const int p = t & 3;
    const float4 bv = ((const float4*)bias)[p];

    for (int nb = n0; nb < n1; nb += 64) {
        int n = nb + (t >> 2);
        bool active = (n < n1);
        int nc = active ? n : (n1 - 1);
        int g = batch[nc];
        float4 h = {0.f, 0.f, 0.f, 0.f};
        if (active) {
            int r0 = row[n];
            int d  = row[n + 1] - r0;
            h = ((const float4*)(B + (size_t)n * HIDDEN))[p];
            for (int i = 0; i < d; ++i) {
                int s = srcidx[r0 + i];
                float4 v = ((const float4*)(B + (size_t)s * HIDDEN))[p];
                h.x += v.x; h.y += v.y; h.z += v.z; h.w += v.w;
            }
            h.x = fmaxf(h.x + bv.x, 0.f);
            h.y = fmaxf(h.y + bv.y, 0.f);
            h.z = fmaxf(h.z + bv.z, 0.f);
            h.w = fmaxf(h.w + bv.w, 0.f);
        }
        int gf = __builtin_amdgcn_readfirstlane(g);
        bool uniform = (__ballot(g == gf) == ~0ull);
        if (uniform) {
            #pragma unroll
            for (int m = 4; m <= 32; m <<= 1) {
                h.x += __shfl_xor(h.x, m, 64);
                h.y += __shfl_xor(h.y, m, 64);
                h.z += __shfl_xor(h.z, m, 64);
                h.w += __shfl_xor(h.w, m, 64);
            }
            if (lane < 4) {
                float* sp = &ssum[gf * HIDDEN + p * 4];
                atomicAdd(sp + 0, h.x);
                atomicAdd(sp + 1, h.y);
                atomicAdd(sp + 2, h.z);
                atomicAdd(sp + 3, h.w);
            }
            if (lane == 0) {
                int wfirst = nb + ((t >> 6) << 4);
                int cnt = min(16, n1 - wfirst);
                if (cnt > 0) atomicAdd(&scnt[gf], (float)cnt);
            }
        } else if (active) {
            float* sp = &ssum[g * HIDDEN + p * 4];
            atomicAdd(sp + 0, h.x);
            atomicAdd(sp + 1, h.y);
            atomicAdd(sp + 2, h.z);
            atomicAdd(sp + 3, h.w);
            if (p == 0) atomicAdd(&scnt[g], 1.f);
        }
    }
    __syncthreads();
    for (int i = t; i < NUM_GRAPHS * HIDDEN; i += 256) {
        float v = ssum[i];
        if (v != 0.f) atomicAdd(&sums[i], v);
    }
    if (t < NUM_GRAPHS) {
        float v = scnt[t];
        if (v != 0.f) atomicAdd(&counts[t], v);
    }
}

// ---------------- FC head ------------------------------------------------------
__global__ __launch_bounds__(256) void k_fc(const float* __restrict__ sums,
                                            const float* __restrict__ counts,
                                            const float* __restrict__ Wfc,
                                            const float* __restrict__ bfc,
                                            float* __restrict__ out) {
    int t = blockIdx.x * 256 + threadIdx.x;
    if (t >= NUM_GRAPHS * NUM_CLS) return;
    int g = t / NUM_CLS, c = t % NUM_CLS;
    float inv = 1.0f / fmaxf(counts[g], 1.0f);
    float acc = bfc[c];
    #pragma unroll
    for (int k = 0; k < HIDDEN; ++k)
        acc += (sums[g * HIDDEN + k] * inv) * Wfc[k * NUM_CLS + c];
    out[t] = acc;
}

extern "C" void kernel_launch(void* const* d_in, const int* in_sizes, int n_in,
                              void* d_out, int out_size, void* d_ws, size_t ws_size,
                              hipStream_t stream) {
    const float* x    = (const float*)d_in[0];
    const int*   ei   = (const int*)d_in[1];   // [2, E] (src row then dst row)
    const int*   batch= (const int*)d_in[2];
    const float* W1   = (const float*)d_in[3];
    const float* b1   = (const float*)d_in[4];
    const float* W2   = (const float*)d_in[5];
    const float* b2   = (const float*)d_in[6];
    const float* Wfc  = (const float*)d_in[7];
    const float* bfc  = (const float*)d_in[8];
    float* out = (float*)d_out;

    const size_t NB = (size_t)N_NODES * HIDDEN * sizeof(float);   // 6.4 MB
    char* ws = (char*)d_ws;
    size_t off = 0;
    float* A      = (float*)(ws + off); off += NB;
    float* B      = (float*)(ws + off); off += NB;
    float* sums   = (float*)(ws + off); off += (size_t)NUM_GRAPHS * HIDDEN * sizeof(float);
    float* counts = (float*)(ws + off); off += (size_t)NUM_GRAPHS * sizeof(float);
    int* row    = (int*)(ws + off); off += (size_t)(N_NODES + 4) * sizeof(int);
    int* cnt    = (int*)(ws + off); off += (size_t)NBUCK * NBLK * sizeof(int);
    int* btot   = (int*)(ws + off); off += (size_t)NBUCK * sizeof(int);
    off = (off + 15) & ~(size_t)15;
    int* srcidx = (int*)(ws + off); off += (size_t)N_EDGES * sizeof(int);
    // packed edge words alias B: place writes / build reads them strictly before
    // k_g1f (stream-ordered) overwrites B.
    unsigned* packed = (unsigned*)B;

    const int gridMM1 = (N_NODES + MM1_ROWS - 1) / MM1_ROWS;
    const int gridG1  = (N_NODES + 63) / 64;
    const int poolChunk = (N_NODES + POOL_BLOCKS - 1) / POOL_BLOCKS;

    // K1: mm1 || bucket histogram (independent work, one launch)
    k_mm1_bcount<<<gridMM1 + NBLK, 256, 0, stream>>>(x, W1, A, ei, cnt,
                                                     N_NODES, gridMM1);
    // K2-K4: CSR build, zero global atomics, zero memsets
    k_bscan<<<NBUCK, 256, 0, stream>>>(cnt, btot, sums);
    k_place<<<NBLK, 256, 0, stream>>>(ei, cnt, btot, packed);
    k_build<<<NBUCK, 256, 0, stream>>>(packed, btot, row, srcidx);

    // K5: layer 1+2 fused: B = relu(A + gather(A) + b1) @ W2
    k_g1f<<<gridG1, 256, 0, stream>>>(row, srcidx, A, b1, W2, B, N_NODES);

    // K6: pool(relu(B + gather(B) + b2)) -> sums/counts ; K7: FC head
    k_g2p<<<POOL_BLOCKS, 256, 0, stream>>>(row, srcidx, B, b2, batch, sums, counts,
                                           N_NODES, poolChunk);
    k_fc<<<(NUM_GRAPHS * NUM_CLS + 255) / 256, 256, 0, stream>>>(sums, counts, Wfc, bfc, out);
}